// Round 4
// baseline (15194.691 us; speedup 1.0000x reference)
//
#include <hip/hip_runtime.h>

// ---------------------------------------------------------------------------
// LSTM network: x_proj GEMM -> persistent-kernel recurrence -> out GEMM -> LSM
// S=8192, I=H=O=1024.  bf16 MFMA compute, f32 state/output.
// R6: R2 poll mapping (512 threads x 1 word, all waves) + PIPELINED polling:
//     4 in-flight sc0+sc1 probes per thread, retired via counted vmcnt(3)
//     ("+v" data-dep pins the compare after the wait).  Sample spacing drops
//     from ~1 RTT to ~RTT/4 -> cuts detect-alignment tail ~500-800 cy/step.
//     Capped at 16 rotations, then vmcnt(0) drain + proven agent-atomic
//     fallback loop (hang-proof; stale tags are monotone -> no false match).
//     Raw lgkmcnt-only barriers kept.  R5's wave-role split reverted (its
//     wave-1 two-word serial poll was the regression).
// ---------------------------------------------------------------------------

using u16 = unsigned short;
using u32 = unsigned int;
using u64 = unsigned long long;

typedef short  short8  __attribute__((ext_vector_type(8)));   // 8 x bf16 frag
typedef float  floatx4 __attribute__((ext_vector_type(4)));
typedef u32    uintx4  __attribute__((ext_vector_type(4)));

#define S_LEN 8192
#define NPROD 64          // producer workgroups in recurrence (H/16)

__device__ __forceinline__ u16 f2bf(float f) {
    u32 u = __float_as_uint(f);
    u += 0x7FFFu + ((u >> 16) & 1u);     // round-to-nearest-even
    return (u16)(u >> 16);
}

__device__ __forceinline__ floatx4 mfma16(short8 a, short8 b, floatx4 c) {
    return __builtin_amdgcn_mfma_f32_16x16x32_bf16(a, b, c, 0, 0, 0);
}

// raw barrier: order LDS ops, leave vmcnt untouched
#define LDS_BARRIER()                                                  \
    do {                                                               \
        asm volatile("s_waitcnt lgkmcnt(0)" ::: "memory");             \
        __builtin_amdgcn_s_barrier();                                  \
        asm volatile("" ::: "memory");                                 \
    } while (0)

// issue one device-coherent probe (bypass L1+L2: cross-XCD fresh at MALL)
#define PROBE(dst, srcp)                                               \
    asm volatile("global_load_dwordx2 %0, %1, off sc0 sc1"             \
                 : "=v"(dst) : "v"(srcp) : "memory")
// wait until the oldest of 4 in-flight probes retired; data-dep on reg
#define PWAIT(reg)                                                     \
    asm volatile("s_waitcnt vmcnt(3)" : "+v"(reg) :: "memory")

// ---------------- conversion / init kernels ----------------

__global__ void cvt_f32_bf16(const float* __restrict__ src, u16* __restrict__ dst, int n) {
    for (int i = blockIdx.x * blockDim.x + threadIdx.x; i < n; i += gridDim.x * blockDim.x)
        dst[i] = f2bf(src[i]);
}

__global__ void bias_comb_k(const float* __restrict__ a, const float* __restrict__ b,
                            float* __restrict__ o) {
    int i = blockIdx.x * blockDim.x + threadIdx.x;
    if (i < 4096) o[i] = a[i] + b[i];
}

__global__ void init_hbuf(u64* __restrict__ hbuf) {
    hbuf[blockIdx.x * 256 + threadIdx.x] = 0ull;   // grid 4 x 256 = 1024 words
}

// ---------------- GEMM: C[m,n] = sum_k A[m,k]*B[n,k] + bias[n] ----------------
// A: [M,K] bf16 row-major; B: [N,K] bf16 row-major; C: [M,N] f32.
// Block tile 128x64 (4 waves of 64x32), mfma 16x16x32 bf16, frags direct from global.

__global__ __launch_bounds__(256) void gemm_bt(const u16* __restrict__ A,
                                               const u16* __restrict__ B,
                                               const float* __restrict__ bias,
                                               float* __restrict__ C,
                                               int M, int N, int K) {
    const int tid = threadIdx.x;
    const int l = tid & 63, w = tid >> 6;
    const int m0 = blockIdx.x * 128 + (w >> 1) * 64;
    const int n0 = blockIdx.y * 64 + (w & 1) * 32;
    const int lr = l & 15, lk = (l >> 4) * 8;

    floatx4 acc[4][2];
#pragma unroll
    for (int i = 0; i < 4; i++)
#pragma unroll
        for (int j = 0; j < 2; j++) acc[i][j] = floatx4{0.f, 0.f, 0.f, 0.f};

    const u16* Ap = A + (size_t)(m0 + lr) * K + lk;
    const u16* Bp = B + (size_t)(n0 + lr) * K + lk;

    for (int k0 = 0; k0 < K; k0 += 32) {
        short8 a0 = *(const short8*)(Ap + k0);
        short8 a1 = *(const short8*)(Ap + (size_t)16 * K + k0);
        short8 a2 = *(const short8*)(Ap + (size_t)32 * K + k0);
        short8 a3 = *(const short8*)(Ap + (size_t)48 * K + k0);
        short8 b0 = *(const short8*)(Bp + k0);
        short8 b1 = *(const short8*)(Bp + (size_t)16 * K + k0);
        acc[0][0] = mfma16(a0, b0, acc[0][0]); acc[0][1] = mfma16(a0, b1, acc[0][1]);
        acc[1][0] = mfma16(a1, b0, acc[1][0]); acc[1][1] = mfma16(a1, b1, acc[1][1]);
        acc[2][0] = mfma16(a2, b0, acc[2][0]); acc[2][1] = mfma16(a2, b1, acc[2][1]);
        acc[3][0] = mfma16(a3, b0, acc[3][0]); acc[3][1] = mfma16(a3, b1, acc[3][1]);
    }

    const int rr = (l >> 4) * 4;
#pragma unroll
    for (int j = 0; j < 2; j++) {
        const int n = n0 + j * 16 + lr;
        const float bv = bias[n];
#pragma unroll
        for (int i = 0; i < 4; i++) {
            const int m = m0 + i * 16 + rr;
#pragma unroll
            for (int r = 0; r < 4; r++)
                C[(size_t)(m + r) * N + n] = acc[i][j][r] + bv;
        }
    }
}

// ---------------- persistent LSTM recurrence ----------------
// 64 WGs x 512 threads (8 waves). WG p owns hidden units [16p, 16p+16).
// Wave w: gate g = w&3, K-half kh = w>>2. A-frags (16 per thread, 64 VGPR)
// live in registers. h exchanged via tagged 64-bit words (hi32 = version,
// lo32 = 2xbf16), parity double-buffered. Every thread polls word tid with
// a 4-deep pipelined probe; agent-atomic fallback guarantees progress.

__device__ __forceinline__ float sig_f(float x) {
    return __builtin_amdgcn_rcpf(1.f + __expf(-x));
}
__device__ __forceinline__ float tanh_f(float x) {
    return 1.f - 2.f * __builtin_amdgcn_rcpf(1.f + __expf(2.f * x));
}

__global__ __launch_bounds__(512, 2) void lstm_rec(const u16* __restrict__ Whhb,
                                                   const float* __restrict__ xp,
                                                   u64* __restrict__ hbuf,
                                                   u32* __restrict__ hs) {
    const int p = blockIdx.x;
    const int tid = threadIdx.x;
    const int l = tid & 63, w = tid >> 6;
    const int g = w & 3;          // gate (i,f,g,o)
    const int kh = w >> 2;        // K half (0: k<512, 1: k>=512)

    __shared__ u32 h_lds[512];    // 1024 bf16 = current h
    __shared__ float dots[128];   // [kh][g*16+jj]

    // preload A-frags: row g*1024 + 16p + (l&15), k = kh*512 + kb*32 + (l>>4)*8
    short8 afr[16];
    {
        const u16* wr = Whhb + (size_t)(g * 1024 + p * 16 + (l & 15)) * 1024
                       + kh * 512 + ((l >> 4) * 8);
#pragma unroll
        for (int kb = 0; kb < 16; ++kb) afr[kb] = *(const short8*)(wr + kb * 32);
    }
    h_lds[tid] = 0u;

    // wave 0 = epilogue/producer wave (lane l: gate l>>4, unit l&15)
    float c_state = 0.f;
    const float* xprow = xp + (size_t)(l >> 4) * 1024 + p * 16 + (l & 15);
    float xpn = (w == 0) ? xprow[0] : 0.f;   // xp(0)
    __syncthreads();     // one-time full barrier

    const int bofs = (l >> 4) * 4;
    const u32* hb_base = &h_lds[kh * 256 + bofs];

    for (int t = 0; t < S_LEN; ++t) {
        float xc = xpn;

        if (w == 0) {
            // issue xp(t+1): in flight under the poll window, retired in it
            int tn = (t + 1 < S_LEN) ? t + 1 : S_LEN - 1;
            xpn = xprow[(size_t)tn * 4096];
        }

        if (t > 0) {    // poll own word of h version t (parity t&1)
            u64* src = hbuf + (size_t)(t & 1) * 512 + tid;
            const u32 want = (u32)t;
            u64 v0, v1, v2, v3, val = 0;
            bool found = false;
            PROBE(v0, src); PROBE(v1, src); PROBE(v2, src); PROBE(v3, src);
            for (int it = 0; it < 16; ++it) {
                PWAIT(v0);
                if (!found && (u32)(v0 >> 32) == want) { val = v0; found = true; }
                if (__all(found)) break;
                PROBE(v0, src);
                PWAIT(v1);
                if (!found && (u32)(v1 >> 32) == want) { val = v1; found = true; }
                if (__all(found)) break;
                PROBE(v1, src);
                PWAIT(v2);
                if (!found && (u32)(v2 >> 32) == want) { val = v2; found = true; }
                if (__all(found)) break;
                PROBE(v2, src);
                PWAIT(v3);
                if (!found && (u32)(v3 >> 32) == want) { val = v3; found = true; }
                if (__all(found)) break;
                PROBE(v3, src);
            }
            // drain dangling probes so their dest regs can be reused safely
            asm volatile("s_waitcnt vmcnt(0)" ::: "memory");
            while (__any(!found)) {        // proven agent-scope fallback
                u64 v = __hip_atomic_load(src, __ATOMIC_RELAXED,
                                          __HIP_MEMORY_SCOPE_AGENT);
                if (!found && (u32)(v >> 32) == want) { val = v; found = true; }
            }
            h_lds[tid] = (u32)val;
        }
        LDS_BARRIER();   // sync1: h(t) complete in LDS

        // matvec over this wave's K-half: 16 MFMAs, 4 chains of 4
        floatx4 ac0 = floatx4{0,0,0,0}, ac1 = floatx4{0,0,0,0};
        floatx4 ac2 = floatx4{0,0,0,0}, ac3 = floatx4{0,0,0,0};
#pragma unroll
        for (int kb = 0; kb < 16; kb += 4) {
            uintx4 b0 = *(const uintx4*)(hb_base + (kb + 0) * 16);
            uintx4 b1 = *(const uintx4*)(hb_base + (kb + 1) * 16);
            uintx4 b2 = *(const uintx4*)(hb_base + (kb + 2) * 16);
            uintx4 b3 = *(const uintx4*)(hb_base + (kb + 3) * 16);
            ac0 = mfma16(afr[kb + 0], __builtin_bit_cast(short8, b0), ac0);
            ac1 = mfma16(afr[kb + 1], __builtin_bit_cast(short8, b1), ac1);
            ac2 = mfma16(afr[kb + 2], __builtin_bit_cast(short8, b2), ac2);
            ac3 = mfma16(afr[kb + 3], __builtin_bit_cast(short8, b3), ac3);
        }
        floatx4 acs = (ac0 + ac1) + (ac2 + ac3);
        if ((l & 15) == 0) {        // column 0 of D holds the dot products
            const int q = l >> 4;
#pragma unroll
            for (int r = 0; r < 4; ++r) dots[kh * 64 + g * 16 + q * 4 + r] = acs[r];
        }
        LDS_BARRIER();   // sync2: dots complete

        if (w == 0) {   // wave-parallel epilogue
            float a = dots[l] + dots[64 + l] + xc;          // lane l: gate l>>4, unit l&15
            float act = ((l >> 4) == 2) ? tanh_f(a) : sig_f(a);
            const int jj = l & 15;
            float fi = __shfl(act, jj);
            float ff = __shfl(act, 16 + jj);
            float fg = __shfl(act, 32 + jj);
            float fo = __shfl(act, 48 + jj);
            if (l < 16) {
                c_state = ff * c_state + fi * fg;
                float h = fo * tanh_f(c_state);
                u16 hb16 = f2bf(h);
                u32 other = (u32)__shfl_down((int)hb16, 1);
                if ((l & 1) == 0) {
                    u32 pk = (u32)hb16 | (other << 16);
                    int pidx = p * 8 + (l >> 1);
                    u64 tv = ((u64)(u32)(t + 1) << 32) | (u64)pk;    // tagged word
                    // order vs the same-parity store 2 steps ago; everything
                    // outstanding here is >= 1 full step old -> ~free
                    asm volatile("s_waitcnt vmcnt(0)" ::: "memory");
                    __hip_atomic_store(&hbuf[(size_t)((t + 1) & 1) * 512 + pidx], tv,
                                       __ATOMIC_RELAXED, __HIP_MEMORY_SCOPE_AGENT);
                    hs[(size_t)t * 512 + pidx] = pk;                 // hs[t] bf16
                }
            }
        }
    }
}

// ---------------- row log_softmax, in place, 1024 cols ----------------

__global__ __launch_bounds__(256) void lsm_k(float* __restrict__ C) {
    const int tid = threadIdx.x;
    float* p = C + (size_t)blockIdx.x * 1024;
    float v0 = p[tid], v1 = p[tid + 256], v2 = p[tid + 512], v3 = p[tid + 768];
    float mx = fmaxf(fmaxf(v0, v1), fmaxf(v2, v3));
#pragma unroll
    for (int o = 1; o < 64; o <<= 1) mx = fmaxf(mx, __shfl_xor(mx, o));
    __shared__ float red[4];
    const int w = tid >> 6, l = tid & 63;
    if (l == 0) red[w] = mx;
    __syncthreads();
    mx = fmaxf(fmaxf(red[0], red[1]), fmaxf(red[2], red[3]));
    float s = __expf(v0 - mx) + __expf(v1 - mx) + __expf(v2 - mx) + __expf(v3 - mx);
#pragma unroll
    for (int o = 1; o < 64; o <<= 1) s += __shfl_xor(s, o);
    __syncthreads();
    if (l == 0) red[w] = s;
    __syncthreads();
    s = red[0] + red[1] + red[2] + red[3];
    float ls = __logf(s) + mx;
    p[tid] = v0 - ls; p[tid + 256] = v1 - ls; p[tid + 512] = v2 - ls; p[tid + 768] = v3 - ls;
}

// ---------------- launch ----------------

extern "C" void kernel_launch(void* const* d_in, const int* in_sizes, int n_in,
                              void* d_out, int out_size, void* d_ws, size_t ws_size,
                              hipStream_t stream) {
    const float* x     = (const float*)d_in[0];
    const float* W_ih  = (const float*)d_in[1];
    const float* W_hh  = (const float*)d_in[2];
    const float* b_ih  = (const float*)d_in[3];
    const float* b_hh  = (const float*)d_in[4];
    const float* W_out = (const float*)d_in[5];
    const float* b_out = (const float*)d_in[6];

    char* ws = (char*)d_ws;
    // workspace layout (bytes)
    u16*   xb    = (u16*)(ws + 0);                     // 8192x1024 bf16   16 MB
    u16*   Wihb  = (u16*)(ws + 16777216);              // 4096x1024 bf16    8 MB
    u16*   Whhb  = (u16*)(ws + 25165824);              // 4096x1024 bf16    8 MB
    u16*   Woutb = (u16*)(ws + 33554432);              // 1024x1024 bf16    2 MB
    float* biasc = (float*)(ws + 35651584);            // 4096 f32         16 KB
    u64*   hbuf  = (u64*)(ws + 35667968);              // 2x512 u64         8 KB
    u32*   hs    = (u32*)(ws + 35676160);              // 8192x512 u32     16 MB
    float* xp    = (float*)(ws + 52453376);            // 8192x4096 f32   128 MB

    init_hbuf<<<4, 256, 0, stream>>>(hbuf);
    cvt_f32_bf16<<<2048, 256, 0, stream>>>(x, xb, 8192 * 1024);
    cvt_f32_bf16<<<1024, 256, 0, stream>>>(W_ih, Wihb, 4096 * 1024);
    cvt_f32_bf16<<<1024, 256, 0, stream>>>(W_hh, Whhb, 4096 * 1024);
    cvt_f32_bf16<<<256, 256, 0, stream>>>(W_out, Woutb, 1024 * 1024);
    bias_comb_k<<<16, 256, 0, stream>>>(b_ih, b_hh, biasc);

    // x_proj = x @ W_ih^T + (b_ih+b_hh)
    gemm_bt<<<dim3(64, 64), 256, 0, stream>>>(xb, Wihb, biasc, xp, 8192, 4096, 1024);

    // recurrence (persistent, 64 WGs, all co-resident)
    lstm_rec<<<NPROD, 512, 0, stream>>>(Whhb, xp, hbuf, hs);

    // logits = hs @ W_out^T + b_out
    gemm_bt<<<dim3(64, 16), 256, 0, stream>>>((const u16*)hs, Woutb, b_out, (float*)d_out,
                                              8192, 1024, 1024);

    // log_softmax rows, in place
    lsm_k<<<8192, 256, 0, stream>>>((float*)d_out);
}

// Round 5
// 13229.446 us; speedup vs baseline: 1.1486x; 1.1486x over previous
//
#include <hip/hip_runtime.h>

// ---------------------------------------------------------------------------
// LSTM network: x_proj GEMM -> persistent-kernel recurrence -> out GEMM -> LSM
// S=8192, I=H=O=1024.  bf16 MFMA compute, f32 state/output.
// R7: R2 structure (best measured) + three surgical deltas:
//   1. poll on waves 1-4 only: each thread polls an ADJACENT PAIR of tagged
//      words with one global_load_dwordx4 sc0 sc1 (single RTT per sample,
//      halves poll messages; freshness of sc0sc1 proven by R6's FETCH data).
//      Bounded fast loop + agent-atomic fallback -> hang-proof.
//   2. wave 0 (epilogue/producer) issues NO vmem in the poll phase: xc comes
//      from LDS; its h-store path is never delayed by load drains.
//   3. wave 5 stages xp into parity-double-buffered LDS; its ~900cy load
//      drains under the poll window (barrier-separated from wave 0's reads).
//   __syncthreads everywhere (per-wave vmcnt drain = proven store ordering).
// ---------------------------------------------------------------------------

using u16 = unsigned short;
using u32 = unsigned int;
using u64 = unsigned long long;

typedef short  short8  __attribute__((ext_vector_type(8)));   // 8 x bf16 frag
typedef float  floatx4 __attribute__((ext_vector_type(4)));
typedef u32    uintx4  __attribute__((ext_vector_type(4)));

#define S_LEN 8192
#define NPROD 64          // producer workgroups in recurrence (H/16)

__device__ __forceinline__ u16 f2bf(float f) {
    u32 u = __float_as_uint(f);
    u += 0x7FFFu + ((u >> 16) & 1u);     // round-to-nearest-even
    return (u16)(u >> 16);
}

__device__ __forceinline__ floatx4 mfma16(short8 a, short8 b, floatx4 c) {
    return __builtin_amdgcn_mfma_f32_16x16x32_bf16(a, b, c, 0, 0, 0);
}

// ---------------- conversion / init kernels ----------------

__global__ void cvt_f32_bf16(const float* __restrict__ src, u16* __restrict__ dst, int n) {
    for (int i = blockIdx.x * blockDim.x + threadIdx.x; i < n; i += gridDim.x * blockDim.x)
        dst[i] = f2bf(src[i]);
}

__global__ void bias_comb_k(const float* __restrict__ a, const float* __restrict__ b,
                            float* __restrict__ o) {
    int i = blockIdx.x * blockDim.x + threadIdx.x;
    if (i < 4096) o[i] = a[i] + b[i];
}

__global__ void init_hbuf(u64* __restrict__ hbuf) {
    hbuf[blockIdx.x * 256 + threadIdx.x] = 0ull;   // grid 4 x 256 = 1024 words
}

// ---------------- GEMM: C[m,n] = sum_k A[m,k]*B[n,k] + bias[n] ----------------
// A: [M,K] bf16 row-major; B: [N,K] bf16 row-major; C: [M,N] f32.
// Block tile 128x64 (4 waves of 64x32), mfma 16x16x32 bf16, frags direct from global.

__global__ __launch_bounds__(256) void gemm_bt(const u16* __restrict__ A,
                                               const u16* __restrict__ B,
                                               const float* __restrict__ bias,
                                               float* __restrict__ C,
                                               int M, int N, int K) {
    const int tid = threadIdx.x;
    const int l = tid & 63, w = tid >> 6;
    const int m0 = blockIdx.x * 128 + (w >> 1) * 64;
    const int n0 = blockIdx.y * 64 + (w & 1) * 32;
    const int lr = l & 15, lk = (l >> 4) * 8;

    floatx4 acc[4][2];
#pragma unroll
    for (int i = 0; i < 4; i++)
#pragma unroll
        for (int j = 0; j < 2; j++) acc[i][j] = floatx4{0.f, 0.f, 0.f, 0.f};

    const u16* Ap = A + (size_t)(m0 + lr) * K + lk;
    const u16* Bp = B + (size_t)(n0 + lr) * K + lk;

    for (int k0 = 0; k0 < K; k0 += 32) {
        short8 a0 = *(const short8*)(Ap + k0);
        short8 a1 = *(const short8*)(Ap + (size_t)16 * K + k0);
        short8 a2 = *(const short8*)(Ap + (size_t)32 * K + k0);
        short8 a3 = *(const short8*)(Ap + (size_t)48 * K + k0);
        short8 b0 = *(const short8*)(Bp + k0);
        short8 b1 = *(const short8*)(Bp + (size_t)16 * K + k0);
        acc[0][0] = mfma16(a0, b0, acc[0][0]); acc[0][1] = mfma16(a0, b1, acc[0][1]);
        acc[1][0] = mfma16(a1, b0, acc[1][0]); acc[1][1] = mfma16(a1, b1, acc[1][1]);
        acc[2][0] = mfma16(a2, b0, acc[2][0]); acc[2][1] = mfma16(a2, b1, acc[2][1]);
        acc[3][0] = mfma16(a3, b0, acc[3][0]); acc[3][1] = mfma16(a3, b1, acc[3][1]);
    }

    const int rr = (l >> 4) * 4;
#pragma unroll
    for (int j = 0; j < 2; j++) {
        const int n = n0 + j * 16 + lr;
        const float bv = bias[n];
#pragma unroll
        for (int i = 0; i < 4; i++) {
            const int m = m0 + i * 16 + rr;
#pragma unroll
            for (int r = 0; r < 4; r++)
                C[(size_t)(m + r) * N + n] = acc[i][j][r] + bv;
        }
    }
}

// ---------------- persistent LSTM recurrence ----------------
// 64 WGs x 512 threads (8 waves). WG p owns hidden units [16p, 16p+16).
// Wave w: gate g = w&3, K-half kh = w>>2. A-frags (16 per thread, 64 VGPR)
// live in registers. h exchanged via tagged 64-bit words (hi32 = version,
// lo32 = 2xbf16), parity double-buffered.
// Roles: waves 1-4 poll (one dwordx4 = word pair each); wave 5 stages xp;
// wave 0 computes epilogue + stores; waves 6,7 only matvec.

__device__ __forceinline__ float sig_f(float x) {
    return __builtin_amdgcn_rcpf(1.f + __expf(-x));
}
__device__ __forceinline__ float tanh_f(float x) {
    return 1.f - 2.f * __builtin_amdgcn_rcpf(1.f + __expf(2.f * x));
}

__global__ __launch_bounds__(512, 2) void lstm_rec(const u16* __restrict__ Whhb,
                                                   const float* __restrict__ xp,
                                                   u64* __restrict__ hbuf,
                                                   u32* __restrict__ hs) {
    const int p = blockIdx.x;
    const int tid = threadIdx.x;
    const int l = tid & 63, w = tid >> 6;
    const int g = w & 3;          // gate (i,f,g,o)
    const int kh = w >> 2;        // K half (0: k<512, 1: k>=512)

    __shared__ u32 h_lds[512];       // 1024 bf16 = current h
    __shared__ float dots[128];      // [kh][g*16+jj]
    __shared__ float xp_lds[2][64];  // xp staged by wave 5, parity buffered

    // preload A-frags: row g*1024 + 16p + (l&15), k = kh*512 + kb*32 + (l>>4)*8
    short8 afr[16];
    {
        const u16* wr = Whhb + (size_t)(g * 1024 + p * 16 + (l & 15)) * 1024
                       + kh * 512 + ((l >> 4) * 8);
#pragma unroll
        for (int kb = 0; kb < 16; ++kb) afr[kb] = *(const short8*)(wr + kb * 32);
    }
    h_lds[tid] = 0u;

    float c_state = 0.f;          // wave 0, lanes < 16
    const float* xprow = xp + (size_t)(l >> 4) * 1024 + p * 16 + (l & 15);
    if (w == 5) xp_lds[0][l] = xprow[0];    // prefill xp(0)
    __syncthreads();

    const int bofs = (l >> 4) * 4;
    const u32* hb_base = &h_lds[kh * 256 + bofs];
    const int pi = (w - 1) * 64 + l;         // pair index (valid for w=1..4)

    for (int t = 0; t < S_LEN; ++t) {
        float xc = 0.f;

        if (w == 0) {
            xc = xp_lds[t & 1][l];           // staged xp(t); no vmem issued
        } else if (w == 5) {
            // stage xp(t+1); load drains under the others' poll window
            int tn = (t + 1 < S_LEN) ? t + 1 : S_LEN - 1;
            xp_lds[(t + 1) & 1][l] = xprow[(size_t)tn * 4096];
        } else if (w <= 4 && t > 0) {
            // poll word pair (2*pi, 2*pi+1) of h version t (parity t&1)
            u64* src0 = hbuf + (size_t)(t & 1) * 512 + 2 * pi;
            const u32 want = (u32)t;
            uintx4 q;
            bool got = false;
            for (int it = 0; it < 4096 && !got; ++it) {
                // one device-coherent 16B sample = both words, single RTT
                asm volatile("global_load_dwordx4 %0, %1, off sc0 sc1\n\t"
                             "s_waitcnt vmcnt(0)"
                             : "=&v"(q) : "v"(src0) : "memory");
                got = (q.y == want) && (q.w == want);
            }
            while (!got) {   // proven agent-scope fallback (hang-proof)
                u64 a = __hip_atomic_load(src0, __ATOMIC_RELAXED,
                                          __HIP_MEMORY_SCOPE_AGENT);
                u64 b = __hip_atomic_load(src0 + 1, __ATOMIC_RELAXED,
                                          __HIP_MEMORY_SCOPE_AGENT);
                if ((u32)(a >> 32) == want && (u32)(b >> 32) == want) {
                    q.x = (u32)a; q.z = (u32)b; got = true;
                }
            }
            h_lds[2 * pi]     = q.x;
            h_lds[2 * pi + 1] = q.z;
        }
        __syncthreads();   // sync1: h(t) complete in LDS

        // matvec over this wave's K-half: 16 MFMAs, 4 chains of 4
        floatx4 ac0 = floatx4{0,0,0,0}, ac1 = floatx4{0,0,0,0};
        floatx4 ac2 = floatx4{0,0,0,0}, ac3 = floatx4{0,0,0,0};
#pragma unroll
        for (int kb = 0; kb < 16; kb += 4) {
            uintx4 b0 = *(const uintx4*)(hb_base + (kb + 0) * 16);
            uintx4 b1 = *(const uintx4*)(hb_base + (kb + 1) * 16);
            uintx4 b2 = *(const uintx4*)(hb_base + (kb + 2) * 16);
            uintx4 b3 = *(const uintx4*)(hb_base + (kb + 3) * 16);
            ac0 = mfma16(afr[kb + 0], __builtin_bit_cast(short8, b0), ac0);
            ac1 = mfma16(afr[kb + 1], __builtin_bit_cast(short8, b1), ac1);
            ac2 = mfma16(afr[kb + 2], __builtin_bit_cast(short8, b2), ac2);
            ac3 = mfma16(afr[kb + 3], __builtin_bit_cast(short8, b3), ac3);
        }
        floatx4 acs = (ac0 + ac1) + (ac2 + ac3);
        if ((l & 15) == 0) {        // column 0 of D holds the dot products
            const int q = l >> 4;
#pragma unroll
            for (int r = 0; r < 4; ++r) dots[kh * 64 + g * 16 + q * 4 + r] = acs[r];
        }
        __syncthreads();   // sync2: dots complete

        if (w == 0) {   // wave-parallel epilogue (lane l: gate l>>4, unit l&15)
            float a = dots[l] + dots[64 + l] + xc;
            float act = ((l >> 4) == 2) ? tanh_f(a) : sig_f(a);
            const int jj = l & 15;
            float fi = __shfl(act, jj);
            float ff = __shfl(act, 16 + jj);
            float fg = __shfl(act, 32 + jj);
            float fo = __shfl(act, 48 + jj);
            if (l < 16) {
                c_state = ff * c_state + fi * fg;
                float h = fo * tanh_f(c_state);
                u16 hb16 = f2bf(h);
                u32 other = (u32)__shfl_down((int)hb16, 1);
                if ((l & 1) == 0) {
                    u32 pk = (u32)hb16 | (other << 16);
                    int pidx = p * 8 + (l >> 1);
                    u64 tv = ((u64)(u32)(t + 1) << 32) | (u64)pk;    // tagged word
                    // same-parity store of 2 steps ago already drained at the
                    // __syncthreads (per-wave vmcnt(0)) barriers in between.
                    __hip_atomic_store(&hbuf[(size_t)((t + 1) & 1) * 512 + pidx], tv,
                                       __ATOMIC_RELAXED, __HIP_MEMORY_SCOPE_AGENT);
                    hs[(size_t)t * 512 + pidx] = pk;                 // hs[t] bf16
                }
            }
        }
    }
}

// ---------------- row log_softmax, in place, 1024 cols ----------------

__global__ __launch_bounds__(256) void lsm_k(float* __restrict__ C) {
    const int tid = threadIdx.x;
    float* p = C + (size_t)blockIdx.x * 1024;
    float v0 = p[tid], v1 = p[tid + 256], v2 = p[tid + 512], v3 = p[tid + 768];
    float mx = fmaxf(fmaxf(v0, v1), fmaxf(v2, v3));
#pragma unroll
    for (int o = 1; o < 64; o <<= 1) mx = fmaxf(mx, __shfl_xor(mx, o));
    __shared__ float red[4];
    const int w = tid >> 6, l = tid & 63;
    if (l == 0) red[w] = mx;
    __syncthreads();
    mx = fmaxf(fmaxf(red[0], red[1]), fmaxf(red[2], red[3]));
    float s = __expf(v0 - mx) + __expf(v1 - mx) + __expf(v2 - mx) + __expf(v3 - mx);
#pragma unroll
    for (int o = 1; o < 64; o <<= 1) s += __shfl_xor(s, o);
    __syncthreads();
    if (l == 0) red[w] = s;
    __syncthreads();
    s = red[0] + red[1] + red[2] + red[3];
    float ls = __logf(s) + mx;
    p[tid] = v0 - ls; p[tid + 256] = v1 - ls; p[tid + 512] = v2 - ls; p[tid + 768] = v3 - ls;
}

// ---------------- launch ----------------

extern "C" void kernel_launch(void* const* d_in, const int* in_sizes, int n_in,
                              void* d_out, int out_size, void* d_ws, size_t ws_size,
                              hipStream_t stream) {
    const float* x     = (const float*)d_in[0];
    const float* W_ih  = (const float*)d_in[1];
    const float* W_hh  = (const float*)d_in[2];
    const float* b_ih  = (const float*)d_in[3];
    const float* b_hh  = (const float*)d_in[4];
    const float* W_out = (const float*)d_in[5];
    const float* b_out = (const float*)d_in[6];

    char* ws = (char*)d_ws;
    // workspace layout (bytes)
    u16*   xb    = (u16*)(ws + 0);                     // 8192x1024 bf16   16 MB
    u16*   Wihb  = (u16*)(ws + 16777216);              // 4096x1024 bf16    8 MB
    u16*   Whhb  = (u16*)(ws + 25165824);              // 4096x1024 bf16    8 MB
    u16*   Woutb = (u16*)(ws + 33554432);              // 1024x1024 bf16    2 MB
    float* biasc = (float*)(ws + 35651584);            // 4096 f32         16 KB
    u64*   hbuf  = (u64*)(ws + 35667968);              // 2x512 u64         8 KB
    u32*   hs    = (u32*)(ws + 35676160);              // 8192x512 u32     16 MB
    float* xp    = (float*)(ws + 52453376);            // 8192x4096 f32   128 MB

    init_hbuf<<<4, 256, 0, stream>>>(hbuf);
    cvt_f32_bf16<<<2048, 256, 0, stream>>>(x, xb, 8192 * 1024);
    cvt_f32_bf16<<<1024, 256, 0, stream>>>(W_ih, Wihb, 4096 * 1024);
    cvt_f32_bf16<<<1024, 256, 0, stream>>>(W_hh, Whhb, 4096 * 1024);
    cvt_f32_bf16<<<256, 256, 0, stream>>>(W_out, Woutb, 1024 * 1024);
    bias_comb_k<<<16, 256, 0, stream>>>(b_ih, b_hh, biasc);

    // x_proj = x @ W_ih^T + (b_ih+b_hh)
    gemm_bt<<<dim3(64, 64), 256, 0, stream>>>(xb, Wihb, biasc, xp, 8192, 4096, 1024);

    // recurrence (persistent, 64 WGs, all co-resident)
    lstm_rec<<<NPROD, 512, 0, stream>>>(Whhb, xp, hbuf, hs);

    // logits = hs @ W_out^T + b_out
    gemm_bt<<<dim3(64, 16), 256, 0, stream>>>((const u16*)hs, Woutb, b_out, (float*)d_out,
                                              8192, 1024, 1024);

    // log_softmax rows, in place
    lsm_k<<<8192, 256, 0, stream>>>((float*)d_out);
}